// Round 12
// baseline (150.914 us; speedup 1.0000x reference)
//
#include <hip/hip_runtime.h>
#include <hip/hip_bf16.h>
#include <math.h>

#define NF     16      // num features
#define INF    1024    // in_f
#define NPROTO 4096
#define NROWS  16384

typedef __attribute__((ext_vector_type(8))) short short8;   // 8 bf16 (4 VGPRs)
typedef __attribute__((ext_vector_type(4))) float f32x4;

// round f32 -> bf16 (RNE) and return as f32 value
__device__ __forceinline__ float bf16_rne(float x) {
    unsigned u = __float_as_uint(x);
    unsigned r = (u + 0x7FFFu + ((u >> 16) & 1u)) & 0xFFFF0000u;
    return __uint_as_float(r);
}

// split f32 v into bf16 hi + bf16 lo (v ~= hi + lo, err ~2^-17 rel)
__device__ __forceinline__ void split_bf16(float v, unsigned short& hi, unsigned short& lo) {
    unsigned u  = __float_as_uint(v);
    unsigned r  = u + 0x7FFFu + ((u >> 16) & 1u);
    hi = (unsigned short)(r >> 16);
    float hf = __uint_as_float(r & 0xFFFF0000u);
    float rem = v - hf;
    unsigned u2 = __float_as_uint(rem);
    unsigned r2 = u2 + 0x7FFFu + ((u2 >> 16) & 1u);
    lo = (unsigned short)(r2 >> 16);
}

__device__ __forceinline__ float sigmoid5(float z) {
    return 1.0f / (1.0f + __expf(-5.0f * z));
}

// Butterfly transpose-reduce: v[64] per lane; afterwards lane L holds
// (sum over all 64 lanes of original v[L]) in v[0].
__device__ __forceinline__ void xreduce64(float* v, int lane) {
#pragma unroll
    for (int s = 32; s >= 1; s >>= 1) {
        bool up = (lane & s) != 0;
#pragma unroll
        for (int j = 0; j < s; ++j) {
            float send = up ? v[j] : v[j + s];
            float recv = __shfl_xor(send, s, 64);
            v[j] = (up ? v[j + s] : v[j]) + recv;
        }
    }
}

// ---------------- Kernel A: build Pe[4096][32] as bf16 hi/lo ----------------
// Pe[o][k]    = |theta|*p_a[o][k] - |alpha|*(1 - p_s[o][k])
// Pe[o][16+k] = -|beta|*p_a[o][k]
__global__ __launch_bounds__(256) void prep_pe(
    const float* __restrict__ proto, const float* __restrict__ feat,
    const float* __restrict__ theta, const float* __restrict__ alpha,
    const float* __restrict__ beta,
    unsigned short* __restrict__ Ph, unsigned short* __restrict__ Pl)
{
    const int lane  = threadIdx.x & 63;
    const int wid   = threadIdx.x >> 6;
    const int rbase = blockIdx.x * 16 + wid * 4;   // 4 rows per wave
    const int i0    = lane * 16;

    const float th = fabsf(theta[0]);
    const float al = fabsf(alpha[0]);
    const float be = fabsf(beta[0]);

    float q[4][16];
#pragma unroll
    for (int r = 0; r < 4; ++r) {
        const float* wrow = proto + (size_t)(rbase + r) * INF + i0;
        float wb[16];
        float asum = 0.f;
#pragma unroll
        for (int j = 0; j < 16; j += 4) {
            float4 w4 = *(const float4*)(wrow + j);
            wb[j+0] = bf16_rne(w4.x); wb[j+1] = bf16_rne(w4.y);
            wb[j+2] = bf16_rne(w4.z); wb[j+3] = bf16_rne(w4.w);
            asum += fabsf(wb[j+0]) + fabsf(wb[j+1])
                  + fabsf(wb[j+2]) + fabsf(wb[j+3]);
        }
        asum += __shfl_xor(asum, 1, 64);
        asum += __shfl_xor(asum, 2, 64);
        float scale = bf16_rne(asum * (1.0f / 64.0f));
        scale = fmaxf(scale, 1e-8f);
        float inv = 1.0f / scale;
#pragma unroll
        for (int j = 0; j < 16; ++j) {
            float t = rintf(bf16_rne(wb[j] * inv));   // jnp.round = half-even
            t = fminf(fmaxf(t, -1.f), 1.f);
            q[r][j] = t * scale;                      // exact in bf16 set
        }
    }

    float acc[64];
#pragma unroll
    for (int i = 0; i < 64; ++i) acc[i] = 0.f;
#pragma unroll
    for (int k = 0; k < NF; ++k) {
        const float* frow = feat + k * INF + i0;
#pragma unroll
        for (int j = 0; j < 16; j += 4) {
            float4 f4 = *(const float4*)(frow + j);
#pragma unroll
            for (int r = 0; r < 4; ++r) {
                acc[r*16+k] = fmaf(q[r][j+0], f4.x, acc[r*16+k]);
                acc[r*16+k] = fmaf(q[r][j+1], f4.y, acc[r*16+k]);
                acc[r*16+k] = fmaf(q[r][j+2], f4.z, acc[r*16+k]);
                acc[r*16+k] = fmaf(q[r][j+3], f4.w, acc[r*16+k]);
            }
        }
    }
    xreduce64(acc, lane);
    float pf = acc[0];
    float ps = sigmoid5(pf);
    float pa = pf * ps;
    int row = rbase + (lane >> 4);
    int k   = lane & 15;
    unsigned short h0, l0, h1, l1;
    split_bf16(th * pa - al * (1.0f - ps), h0, l0);
    split_bf16(-be * pa, h1, l1);
    Ph[row * 32 + k]      = h0;  Pl[row * 32 + k]      = l0;
    Ph[row * 32 + 16 + k] = h1;  Pl[row * 32 + 16 + k] = l1;
}

// ---- Fused main: block = 1 wave owns 16 output rows x ALL 4096 cols ----
// Phase 1: compute this block's 16 Xe rows (butterfly), park bf16 hi/lo in
//          LDS (2 KiB). No barriers — single wave, lgkmcnt covers RAW.
// Phase 2: B-frags from LDS; 16 col-chunks x {A-frags (L2), 64 MFMA,
//          XOR-swizzled LDS transpose, 16 NT 1KB-contiguous row stores}.
// x read exactly once (67 MB); Xe global round-trip eliminated; prep work
// distributed across 1024 independent blocks instead of a serial dispatch.
__global__ __launch_bounds__(64) void fused_main(
    const float* __restrict__ x, const float* __restrict__ feat,
    const unsigned short* __restrict__ Ph, const unsigned short* __restrict__ Pl,
    float* __restrict__ out)
{
    __shared__ float ldsT[16][256];                     // 16 KiB transpose buf
    __shared__ unsigned short XeH[16][32], XeL[16][32]; // 2 KiB Xe tile

    const int lane = threadIdx.x & 63;
    int bid = (int)blockIdx.x;
    bid = (bid & 7) * 128 + (bid >> 3);   // XCD-contiguous swizzle (1024%8==0)
    const int nbase = bid * 16;
    const int m  = lane & 15;
    const int b  = lane >> 4;
    const int i0 = lane * 16;

    // ---- Phase 1: Xe for rows [nbase, nbase+16) ----
#pragma unroll 1
    for (int c4 = 0; c4 < 4; ++c4) {
        const int rbase = nbase + c4 * 4;
        float4 xv[4][4];
#pragma unroll
        for (int r = 0; r < 4; ++r) {
            const float* xrow = x + (size_t)(rbase + r) * INF + i0;
#pragma unroll
            for (int j = 0; j < 4; ++j) xv[r][j] = *(const float4*)(xrow + j * 4);
        }
        float acc[64];
#pragma unroll
        for (int i = 0; i < 64; ++i) acc[i] = 0.f;
#pragma unroll
        for (int k = 0; k < NF; ++k) {
            const float* frow = feat + k * INF + i0;
#pragma unroll
            for (int j = 0; j < 4; ++j) {
                float4 f4 = *(const float4*)(frow + j * 4);
#pragma unroll
                for (int r = 0; r < 4; ++r) {
                    acc[r*16+k] = fmaf(xv[r][j].x, f4.x, acc[r*16+k]);
                    acc[r*16+k] = fmaf(xv[r][j].y, f4.y, acc[r*16+k]);
                    acc[r*16+k] = fmaf(xv[r][j].z, f4.z, acc[r*16+k]);
                    acc[r*16+k] = fmaf(xv[r][j].w, f4.w, acc[r*16+k]);
                }
            }
        }
        xreduce64(acc, lane);
        float xf = acc[0];
        float xs = sigmoid5(xf);
        int row = c4 * 4 + (lane >> 4);
        int k   = lane & 15;
        unsigned short h0, l0, h1, l1;
        split_bf16(xf * xs, h0, l0);
        split_bf16(1.0f - xs, h1, l1);
        XeH[row][k]      = h0;  XeL[row][k]      = l0;
        XeH[row][16 + k] = h1;  XeL[row][16 + k] = l1;
    }

    // ---- B fragments from LDS (constant for all 16 col-chunks) ----
    const short8 Bh = *(const short8*)&XeH[m][b * 8];
    const short8 Bl = *(const short8*)&XeL[m][b * 8];

    // ---- Phase 2: 16 col-chunks of 256 ----
    const int wsw = 4 * (m & 7);
    float* myrow = &ldsT[m][0];
#pragma unroll 1
    for (int c = 0; c < 16; ++c) {
        const int ob = c * 256;
#pragma unroll
        for (int t = 0; t < 16; ++t) {
            const size_t aoff = (size_t)(ob + t * 16 + m) * 32 + b * 8;
            const short8 Ah = *(const short8*)(Ph + aoff);
            const short8 Al = *(const short8*)(Pl + aoff);
            f32x4 acc = {0.f, 0.f, 0.f, 0.f};
            acc = __builtin_amdgcn_mfma_f32_16x16x32_bf16(Ah, Bh, acc, 0, 0, 0);
            acc = __builtin_amdgcn_mfma_f32_16x16x32_bf16(Ah, Bl, acc, 0, 0, 0);
            acc = __builtin_amdgcn_mfma_f32_16x16x32_bf16(Al, Bh, acc, 0, 0, 0);
            acc = __builtin_amdgcn_mfma_f32_16x16x32_bf16(Al, Bl, acc, 0, 0, 0);
            *(f32x4*)(myrow + ((t * 16 + b * 4) ^ wsw)) = acc;  // 4-aligned XOR
        }
        const float* src = &ldsT[0][0];
#pragma unroll
        for (int r = 0; r < 16; ++r) {
            f32x4 v = *(const f32x4*)(src + r * 256 + ((lane * 4) ^ (4 * (r & 7))));
            f32x4* dst = (f32x4*)(out + (size_t)(nbase + r) * NPROTO + ob + lane * 4);
            __builtin_nontemporal_store(v, dst);
        }
    }
}

extern "C" void kernel_launch(void* const* d_in, const int* in_sizes, int n_in,
                              void* d_out, int out_size, void* d_ws, size_t ws_size,
                              hipStream_t stream) {
    const float* x     = (const float*)d_in[0];
    const float* feat  = (const float*)d_in[1];
    const float* proto = (const float*)d_in[2];
    const float* theta = (const float*)d_in[3];
    const float* alpha = (const float*)d_in[4];
    const float* beta  = (const float*)d_in[5];
    float* out = (float*)d_out;

    unsigned short* Ph = (unsigned short*)d_ws;          // 256 KiB
    unsigned short* Pl = Ph + (size_t)NPROTO * 32;       // 256 KiB

    prep_pe<<<dim3(NPROTO / 16), 256, 0, stream>>>(proto, feat, theta, alpha, beta, Ph, Pl);
    fused_main<<<dim3(NROWS / 16), 64, 0, stream>>>(x, feat, Ph, Pl, out);
}

// Round 14
// 116.163 us; speedup vs baseline: 1.2992x; 1.2992x over previous
//
#include <hip/hip_runtime.h>
#include <hip/hip_bf16.h>
#include <math.h>

#define NF     16      // num features (K of low-rank projection)
#define INF    1024    // in_f
#define NPROTO 4096
#define NROWS  16384

typedef __attribute__((ext_vector_type(8))) short short8;   // 8 bf16 (4 VGPRs)
typedef __attribute__((ext_vector_type(4))) float f32x4;
typedef __attribute__((ext_vector_type(2))) float f32x2;

// round f32 -> bf16 (RNE) and return as f32 value
__device__ __forceinline__ float bf16_rne(float x) {
    unsigned u = __float_as_uint(x);
    unsigned r = (u + 0x7FFFu + ((u >> 16) & 1u)) & 0xFFFF0000u;
    return __uint_as_float(r);
}

// split f32 v into bf16 hi + bf16 lo (v ~= hi + lo, err ~2^-17 rel)
__device__ __forceinline__ void split_bf16(float v, unsigned short& hi, unsigned short& lo) {
    unsigned u  = __float_as_uint(v);
    unsigned r  = u + 0x7FFFu + ((u >> 16) & 1u);
    hi = (unsigned short)(r >> 16);
    float hf = __uint_as_float(r & 0xFFFF0000u);
    float rem = v - hf;
    unsigned u2 = __float_as_uint(rem);
    unsigned r2 = u2 + 0x7FFFu + ((u2 >> 16) & 1u);
    lo = (unsigned short)(r2 >> 16);
}

__device__ __forceinline__ float sigmoid5(float z) {
    return 1.0f / (1.0f + __expf(-5.0f * z));
}

// Butterfly transpose-reduce: v[64] per lane; afterwards lane L holds
// (sum over all 64 lanes of original v[L]) in v[0].
__device__ __forceinline__ void xreduce64(float* v, int lane) {
#pragma unroll
    for (int s = 32; s >= 1; s >>= 1) {
        bool up = (lane & s) != 0;
#pragma unroll
        for (int j = 0; j < s; ++j) {
            float send = up ? v[j] : v[j + s];
            float recv = __shfl_xor(send, s, 64);
            v[j] = (up ? v[j + s] : v[j]) + recv;
        }
    }
}

// ---------------- prep part A: Pe rows -> bf16 hi/lo ----------------
__device__ __forceinline__ void do_build_pe(
    int blk,
    const float* __restrict__ proto, const float* __restrict__ feat,
    const float* __restrict__ theta, const float* __restrict__ alpha,
    const float* __restrict__ beta,
    unsigned short* __restrict__ Ph, unsigned short* __restrict__ Pl)
{
    const int lane  = threadIdx.x & 63;
    const int wid   = threadIdx.x >> 6;
    const int rbase = blk * 16 + wid * 4;   // 4 rows per wave
    const int i0    = lane * 16;

    const float th = fabsf(theta[0]);
    const float al = fabsf(alpha[0]);
    const float be = fabsf(beta[0]);

    float q[4][16];
#pragma unroll
    for (int r = 0; r < 4; ++r) {
        const float* wrow = proto + (size_t)(rbase + r) * INF + i0;
        float wb[16];
        float asum = 0.f;
#pragma unroll
        for (int j = 0; j < 16; j += 4) {
            float4 w4 = *(const float4*)(wrow + j);
            wb[j+0] = bf16_rne(w4.x); wb[j+1] = bf16_rne(w4.y);
            wb[j+2] = bf16_rne(w4.z); wb[j+3] = bf16_rne(w4.w);
            asum += fabsf(wb[j+0]) + fabsf(wb[j+1])
                  + fabsf(wb[j+2]) + fabsf(wb[j+3]);
        }
        asum += __shfl_xor(asum, 1, 64);
        asum += __shfl_xor(asum, 2, 64);
        float scale = bf16_rne(asum * (1.0f / 64.0f));
        scale = fmaxf(scale, 1e-8f);
        float inv = 1.0f / scale;
#pragma unroll
        for (int j = 0; j < 16; ++j) {
            float t = rintf(bf16_rne(wb[j] * inv));   // jnp.round = half-even
            t = fminf(fmaxf(t, -1.f), 1.f);
            q[r][j] = t * scale;                      // exact in bf16 set
        }
    }

    float acc[64];
#pragma unroll
    for (int i = 0; i < 64; ++i) acc[i] = 0.f;
#pragma unroll
    for (int k = 0; k < NF; ++k) {
        const float* frow = feat + k * INF + i0;
#pragma unroll
        for (int j = 0; j < 16; j += 4) {
            float4 f4 = *(const float4*)(frow + j);
#pragma unroll
            for (int r = 0; r < 4; ++r) {
                acc[r*16+k] = fmaf(q[r][j+0], f4.x, acc[r*16+k]);
                acc[r*16+k] = fmaf(q[r][j+1], f4.y, acc[r*16+k]);
                acc[r*16+k] = fmaf(q[r][j+2], f4.z, acc[r*16+k]);
                acc[r*16+k] = fmaf(q[r][j+3], f4.w, acc[r*16+k]);
            }
        }
    }
    xreduce64(acc, lane);
    float pf = acc[0];
    float ps = sigmoid5(pf);
    float pa = pf * ps;
    int row = rbase + (lane >> 4);
    int k   = lane & 15;
    unsigned short h0, l0, h1, l1;
    split_bf16(th * pa - al * (1.0f - ps), h0, l0);
    split_bf16(-be * pa, h1, l1);
    Ph[row * 32 + k]      = h0;  Pl[row * 32 + k]      = l0;
    Ph[row * 32 + 16 + k] = h1;  Pl[row * 32 + 16 + k] = l1;
}

// ---------------- prep part B: Xe rows -> bf16 hi/lo ----------------
__device__ __forceinline__ void do_build_xe(
    int blk,
    const float* __restrict__ x, const float* __restrict__ feat,
    unsigned short* __restrict__ Xh, unsigned short* __restrict__ Xl)
{
    const int lane  = threadIdx.x & 63;
    const int wid   = threadIdx.x >> 6;
    const int rbase = blk * 16 + wid * 4;
    const int i0    = lane * 16;

    float4 xv[4][4];
#pragma unroll
    for (int r = 0; r < 4; ++r) {
        const float* xrow = x + (size_t)(rbase + r) * INF + i0;
#pragma unroll
        for (int j = 0; j < 4; ++j) xv[r][j] = *(const float4*)(xrow + j * 4);
    }

    float acc[64];
#pragma unroll
    for (int i = 0; i < 64; ++i) acc[i] = 0.f;
#pragma unroll
    for (int k = 0; k < NF; ++k) {
        const float* frow = feat + k * INF + i0;
#pragma unroll
        for (int j = 0; j < 4; ++j) {
            float4 f4 = *(const float4*)(frow + j * 4);
#pragma unroll
            for (int r = 0; r < 4; ++r) {
                acc[r*16+k] = fmaf(xv[r][j].x, f4.x, acc[r*16+k]);
                acc[r*16+k] = fmaf(xv[r][j].y, f4.y, acc[r*16+k]);
                acc[r*16+k] = fmaf(xv[r][j].z, f4.z, acc[r*16+k]);
                acc[r*16+k] = fmaf(xv[r][j].w, f4.w, acc[r*16+k]);
            }
        }
    }
    xreduce64(acc, lane);
    float xf = acc[0];
    float xs = sigmoid5(xf);
    int row = rbase + (lane >> 4);
    int k   = lane & 15;
    unsigned short h0, l0, h1, l1;
    split_bf16(xf * xs, h0, l0);
    split_bf16(1.0f - xs, h1, l1);
    Xh[row * 32 + k]      = h0;  Xl[row * 32 + k]      = l0;
    Xh[row * 32 + 16 + k] = h1;  Xl[row * 32 + 16 + k] = l1;
}

// Fused prep: blocks [0,256) build Pe, blocks [256,1280) build Xe.
__global__ __launch_bounds__(256) void prep(
    const float* __restrict__ x, const float* __restrict__ feat,
    const float* __restrict__ proto,
    const float* __restrict__ theta, const float* __restrict__ alpha,
    const float* __restrict__ beta,
    unsigned short* __restrict__ Ph, unsigned short* __restrict__ Pl,
    unsigned short* __restrict__ Xh, unsigned short* __restrict__ Xl)
{
    const int blk = blockIdx.x;
    if (blk < NPROTO / 16) {
        do_build_pe(blk, proto, feat, theta, alpha, beta, Ph, Pl);
    } else {
        do_build_xe(blk - NPROTO / 16, x, feat, Xh, Xl);
    }
}

// ------- main: out = Xe (16384x32) @ Pe^T (4096x32), MFMA hi/lo -------
// R13: SAME structure as R9 (leader), tile halved to 16 rows x 128 cols:
// 8 KiB LDS/wave -> 20 blocks/CU (5 waves/SIMD, was 2.5), fewer live VGPRs.
// The extra resident waves are the latency-hiding TLP every prior variant
// lacked. Stores: 16 NT dwordx2, each 512 B contiguous in one row.
__global__ __launch_bounds__(64) void main_mm_mfma(
    const unsigned short* __restrict__ Xh, const unsigned short* __restrict__ Xl,
    const unsigned short* __restrict__ Ph, const unsigned short* __restrict__ Pl,
    float* __restrict__ out)
{
    __shared__ float lds[16][128];      // 8 KiB, wave-private (1 wave/block)
    const int lane  = threadIdx.x & 63;
    const int m     = lane & 15;        // n within tile (C col)
    const int b     = lane >> 4;        // K-group / C row-group
    const int nbase = blockIdx.y * 16;
    const int ob    = blockIdx.x * 128;

    // B fragment (Xe): col = n, loaded once per wave
    const size_t boff = (size_t)(nbase + m) * 32 + b * 8;
    const short8 Bh = *(const short8*)(Xh + boff);
    const short8 Bl = *(const short8*)(Xl + boff);

    // col-XOR swizzle: logical dword c of row r stored at c ^ (4*(r&7))
    const int wsw = 4 * (m & 7);
    float* myrow = &lds[m][0];
#pragma unroll
    for (int t = 0; t < 8; ++t) {
        const size_t aoff = (size_t)(ob + t * 16 + m) * 32 + b * 8;
        const short8 Ah = *(const short8*)(Ph + aoff);
        const short8 Al = *(const short8*)(Pl + aoff);
        f32x4 acc = {0.f, 0.f, 0.f, 0.f};
        acc = __builtin_amdgcn_mfma_f32_16x16x32_bf16(Ah, Bh, acc, 0, 0, 0);
        acc = __builtin_amdgcn_mfma_f32_16x16x32_bf16(Ah, Bl, acc, 0, 0, 0);
        acc = __builtin_amdgcn_mfma_f32_16x16x32_bf16(Al, Bh, acc, 0, 0, 0);
        acc = __builtin_amdgcn_mfma_f32_16x16x32_bf16(Al, Bl, acc, 0, 0, 0);
        *(f32x4*)(myrow + ((t * 16 + b * 4) ^ wsw)) = acc;  // 4-aligned XOR, <128
    }

    const float* src = &lds[0][0];
#pragma unroll
    for (int r = 0; r < 16; ++r) {
        f32x2 v = *(const f32x2*)(src + r * 128 + ((lane * 2) ^ (4 * (r & 7))));
        f32x2* dst = (f32x2*)(out + (size_t)(nbase + r) * NPROTO + ob + lane * 2);
        __builtin_nontemporal_store(v, dst);
    }
}

extern "C" void kernel_launch(void* const* d_in, const int* in_sizes, int n_in,
                              void* d_out, int out_size, void* d_ws, size_t ws_size,
                              hipStream_t stream) {
    const float* x     = (const float*)d_in[0];
    const float* feat  = (const float*)d_in[1];
    const float* proto = (const float*)d_in[2];
    const float* theta = (const float*)d_in[3];
    const float* alpha = (const float*)d_in[4];
    const float* beta  = (const float*)d_in[5];
    float* out = (float*)d_out;

    unsigned short* Ph = (unsigned short*)d_ws;          // 256 KiB
    unsigned short* Pl = Ph + (size_t)NPROTO * 32;       // 256 KiB
    unsigned short* Xh = Pl + (size_t)NPROTO * 32;       // 1 MiB
    unsigned short* Xl = Xh + (size_t)NROWS * 32;        // 1 MiB

    prep<<<dim3(NPROTO / 16 + NROWS / 16), 256, 0, stream>>>(
        x, feat, proto, theta, alpha, beta, Ph, Pl, Xh, Xl);
    main_mm_mfma<<<dim3(NPROTO / 128, NROWS / 16), 64, 0, stream>>>(Xh, Xl, Ph, Pl, out);
}